// Round 7
// baseline (128.505 us; speedup 1.0000x reference)
//
#include <hip/hip_runtime.h>

// Chamfer distance via MFMA (R5-VERIFIED dataflow: owned points = A operand
// (C/D rows), staged points = B operand via LDS (C/D cols = lane&31)).
// One v_mfma_f32_32x32x16_bf16 per 32x32 tile, K-slot packing (K=16):
//   coord c: A slots [ch,ch,cl,cl], B slots [qh,ql,qh,ql], q=-2t
//     -> (ch+cl)(qh+ql) = -2 c_p c_t exactly (bf16*bf16 products exact in f32)
//   norms:   A [n2h,n2l,1,1], B [1,1,n2h,n2l] -> |p|^2+|t|^2
// MFMA output IS d_ij; hi/lo split err ~3e-5 << 6.2e-4 threshold.
//
// R7 schedule changes vs R5 (convention unchanged): 4 A-frags/wave, 32 KB
// single-stage LDS, grid 1024 blocks = 4/CU = 16 waves/CU, 2-stage reduce.

typedef short s16x8 __attribute__((ext_vector_type(8)));
typedef float f32x16 __attribute__((ext_vector_type(16)));

static __device__ __forceinline__ unsigned short f2bf(float f) {
    unsigned u = __float_as_uint(f);
    unsigned r = (u + 0x7FFFu + ((u >> 16) & 1u)) >> 16;  // RNE
    return (unsigned short)r;
}
static __device__ __forceinline__ float bf2f(unsigned short h) {
    return __uint_as_float(((unsigned)h) << 16);
}
static __device__ __forceinline__ void split2(float v, unsigned short& h, unsigned short& l) {
    h = f2bf(v);
    l = f2bf(v - bf2f(h));
}

union Pack16 { unsigned short u[16]; uint4 v[2]; };

// A-pack (coords + n2) and B-pack (-2*coords + n2) per point, both clouds.
// Layout: [point][16] bf16 = 32 B per point (2 uint4 = k-half 0, k-half 1).
__global__ void prep_pack(const float* __restrict__ predict, const float* __restrict__ target,
                          unsigned short* __restrict__ ApP, unsigned short* __restrict__ BpP,
                          unsigned short* __restrict__ ApT, unsigned short* __restrict__ BpT,
                          int N)
{
    int i = blockIdx.x * blockDim.x + threadIdx.x;
    if (i >= 2 * N) return;
    const float* src = (i < N) ? predict : target;
    unsigned short* Ap = (i < N) ? ApP : ApT;
    unsigned short* Bp = (i < N) ? BpP : BpT;
    int j = (i < N) ? i : i - N;

    float x = src[3*j], y = src[3*j+1], z = src[3*j+2];
    float n2 = __builtin_fmaf(x, x, __builtin_fmaf(y, y, z*z));

    unsigned short xh,xl,yh,yl,zh,zl,nh,nl,qxh,qxl,qyh,qyl,qzh,qzl;
    split2(x, xh, xl); split2(y, yh, yl); split2(z, zh, zl); split2(n2, nh, nl);
    split2(-2.0f*x, qxh, qxl); split2(-2.0f*y, qyh, qyl); split2(-2.0f*z, qzh, qzl);
    const unsigned short one = f2bf(1.0f);

    Pack16 a, b;
    a.u[0]=xh; a.u[1]=xh; a.u[2]=xl; a.u[3]=xl;
    a.u[4]=yh; a.u[5]=yh; a.u[6]=yl; a.u[7]=yl;
    a.u[8]=zh; a.u[9]=zh; a.u[10]=zl; a.u[11]=zl;
    a.u[12]=nh; a.u[13]=nl; a.u[14]=one; a.u[15]=one;

    b.u[0]=qxh; b.u[1]=qxl; b.u[2]=qxh; b.u[3]=qxl;
    b.u[4]=qyh; b.u[5]=qyl; b.u[6]=qyh; b.u[7]=qyl;
    b.u[8]=qzh; b.u[9]=qzl; b.u[10]=qzh; b.u[11]=qzl;
    b.u[12]=one; b.u[13]=one; b.u[14]=nh; b.u[15]=nl;

    uint4* ad = (uint4*)(Ap + (size_t)j * 16);
    uint4* bd = (uint4*)(Bp + (size_t)j * 16);
    ad[0] = a.v[0]; ad[1] = a.v[1];
    bd[0] = b.v[0]; bd[1] = b.v[1];
}

#define TPB   256
#define AFRAG 4                           // A-frags (32-row strips) per wave
#define ROWS_PER_BLOCK (AFRAG * 32 * 4)   // 512 (4 waves)
#define SCOLS 1024                        // staged cols per block, 32 KB LDS
#define CGROUPS 16                        // 16384 / 1024

// Grid (N/512, CGROUPS, 2). partials[slot][row], slot = dir*16 + cgroup.
__global__ __launch_bounds__(TPB, 4) void chamfer_main(
    const unsigned short* __restrict__ ApP, const unsigned short* __restrict__ BpP,
    const unsigned short* __restrict__ ApT, const unsigned short* __restrict__ BpT,
    float* __restrict__ partials, int N)
{
    const int dir = blockIdx.z;
    // dir 0: owned rows = predict (Ap), staged cols = target (Bp) -> dist1
    // dir 1: owned rows = target,       staged cols = predict     -> dist2
    const unsigned short* __restrict__ Ap = dir ? ApT : ApP;
    const unsigned short* __restrict__ Bp = dir ? BpP : BpT;

    __shared__ unsigned short lB[SCOLS * 16];   // 32 KB, point-order (as R5)

    const int tid  = threadIdx.x;
    const int w    = tid >> 6;
    const int lane = tid & 63;
    const int lm   = lane & 31;
    const int lg   = lane >> 5;

    // Stage this block's 1024 staged points: straight copy, 8 uint4/thread.
    const uint4* gB = (const uint4*)Bp + (size_t)blockIdx.y * (SCOLS * 2);
    uint4* l4 = (uint4*)lB;
    #pragma unroll
    for (int it = 0; it < (SCOLS * 2) / TPB; ++it)
        l4[it * TPB + tid] = gB[it * TPB + tid];

    // Owned A-fragments: 4 strips of 32 rows per wave (128 rows/wave).
    const int rowbase = blockIdx.x * ROWS_PER_BLOCK + w * (AFRAG * 32);
    const uint4* A4 = (const uint4*)Ap;
    s16x8 af[AFRAG];
    #pragma unroll
    for (int f = 0; f < AFRAG; ++f)
        af[f] = __builtin_bit_cast(s16x8, A4[(size_t)(rowbase + f * 32 + lm) * 2 + lg]);

    __syncthreads();

    float rm[AFRAG][16];
    #pragma unroll
    for (int f = 0; f < AFRAG; ++f)
        #pragma unroll
        for (int r = 0; r < 16; ++r) rm[f][r] = 3.0e38f;

    const f32x16 zc = {0.f,0.f,0.f,0.f,0.f,0.f,0.f,0.f,0.f,0.f,0.f,0.f,0.f,0.f,0.f,0.f};

    #pragma unroll 4
    for (int t = 0; t < SCOLS / 32; ++t) {   // 32 col-tiles
        // B fragment (verified R5 addressing): col point = t*32+lm, half lg.
        uint4 bv = *(const uint4*)(lB + t * 512 + lm * 16 + lg * 8);
        s16x8 b = __builtin_bit_cast(s16x8, bv);
        #pragma unroll
        for (int f = 0; f < AFRAG; ++f) {
            f32x16 acc = __builtin_amdgcn_mfma_f32_32x32x16_bf16(af[f], b, zc, 0, 0, 0);
            #pragma unroll
            for (int r = 0; r < 16; ++r)
                rm[f][r] = fminf(rm[f][r], acc[r]);   // per-row running min
        }
    }

    // Butterfly min over the 32 col-lanes (bits 0..4; halves hold disjoint rows).
    #pragma unroll
    for (int m = 1; m <= 16; m <<= 1) {
        #pragma unroll
        for (int f = 0; f < AFRAG; ++f)
            #pragma unroll
            for (int r = 0; r < 16; ++r)
                rm[f][r] = fminf(rm[f][r], __shfl_xor(rm[f][r], m, 64));
    }

    // C/D row decode (verified m74/m101 + R5): row = (r&3)+8*(r>>2)+4*lg.
    const int slot = dir * CGROUPS + blockIdx.y;
    #pragma unroll
    for (int r = 0; r < 16; ++r) {
        int rl = (r & 3) + 8 * (r >> 2) + 4 * lg;
        if (lm == r) {
            #pragma unroll
            for (int f = 0; f < AFRAG; ++f)
                partials[(size_t)slot * N + rowbase + f * 32 + rl] = rm[f][r];
        }
    }
}

// Stage 1: per-row min over CGROUPS slots per dir, clamp, sum -> double/block.
__global__ __launch_bounds__(256) void chamfer_reduce1(
    const float* __restrict__ partials, double* __restrict__ bsum, int N)
{
    const int tid = threadIdx.x;
    const int row = blockIdx.x * 256 + tid;
    float m0 = 3.0e38f, m1 = 3.0e38f;
    #pragma unroll
    for (int k = 0; k < CGROUPS; ++k) {
        m0 = fminf(m0, partials[(size_t)k * N + row]);
        m1 = fminf(m1, partials[(size_t)(CGROUPS + k) * N + row]);
    }
    double s = (double)fmaxf(m0, 0.0f) + (double)fmaxf(m1, 0.0f);
    for (int off = 32; off; off >>= 1) s += __shfl_down(s, off, 64);
    __shared__ double sacc[4];
    if ((tid & 63) == 0) sacc[tid >> 6] = s;
    __syncthreads();
    if (tid == 0) bsum[blockIdx.x] = sacc[0] + sacc[1] + sacc[2] + sacc[3];
}

// Stage 2: sum 64 block partials, write mean(dist1)+mean(dist2).
__global__ void chamfer_reduce2(const double* __restrict__ bsum,
                                float* __restrict__ out, int N) {
    double s = bsum[threadIdx.x];   // 64 threads
    for (int off = 32; off; off >>= 1) s += __shfl_down(s, off, 64);
    if (threadIdx.x == 0) out[0] = (float)(s / (double)N);
}

extern "C" void kernel_launch(void* const* d_in, const int* in_sizes, int n_in,
                              void* d_out, int out_size, void* d_ws, size_t ws_size,
                              hipStream_t stream) {
    const float* predict = (const float*)d_in[0];
    const float* target  = (const float*)d_in[1];
    const int N = in_sizes[0] / 3;   // 16384

    unsigned short* ws16 = (unsigned short*)d_ws;
    unsigned short* ApP = ws16;
    unsigned short* BpP = ws16 + (size_t)1 * N * 16;
    unsigned short* ApT = ws16 + (size_t)2 * N * 16;
    unsigned short* BpT = ws16 + (size_t)3 * N * 16;
    float* partials = (float*)(ws16 + (size_t)4 * N * 16);        // 32*N floats
    double* bsum    = (double*)(partials + (size_t)32 * N);       // 64 doubles

    prep_pack<<<dim3((2 * N + 255) / 256), dim3(256), 0, stream>>>(
        predict, target, ApP, BpP, ApT, BpT, N);

    dim3 grid(N / ROWS_PER_BLOCK, CGROUPS, 2);   // 32 x 16 x 2 = 1024 blocks
    chamfer_main<<<grid, dim3(TPB), 0, stream>>>(ApP, BpP, ApT, BpT, partials, N);

    chamfer_reduce1<<<dim3(N / 256), dim3(256), 0, stream>>>(partials, bsum, N);
    chamfer_reduce2<<<dim3(1), dim3(64), 0, stream>>>(bsum, (float*)d_out, N);
}

// Round 8
// 87.080 us; speedup vs baseline: 1.4757x; 1.4757x over previous
//
#include <hip/hip_runtime.h>

// Chamfer distance via MFMA (R5/R7-VERIFIED dataflow: owned points = A operand
// (C/D rows), staged points = B operand via LDS (C/D cols = lane&31)).
// One v_mfma_f32_32x32x16_bf16 per 32x32 tile, K-slot packing (K=16):
//   coord c: A slots [ch,ch,cl,cl], B slots [qh,ql,qh,ql], q=-2t
//     -> (ch+cl)(qh+ql) = -2 c_p c_t exactly (bf16*bf16 products exact in f32)
//   norms:   A [n2h,n2l,1,1], B [1,1,n2h,n2l] -> |p|^2+|t|^2
// MFMA output IS d_ij; hi/lo split err ~3e-5 << 6.2e-4 threshold.
//
// R8 vs R7 (dataflow unchanged):
//  - AFRAG 4->2, TPB 256->512, __launch_bounds__(512,4): kills the VGPR spill
//    (R7: VGPR capped 64, 166 MB scratch writes).
//  - LDS restaged [tile][khalf][lane]: wave ds_read_b128 linear in lane ->
//    2 lanes/bank (free) vs R7's 4-way conflict (SQ_LDS_BANK_CONFLICT=4x reads).

typedef short s16x8 __attribute__((ext_vector_type(8)));
typedef float f32x16 __attribute__((ext_vector_type(16)));

static __device__ __forceinline__ unsigned short f2bf(float f) {
    unsigned u = __float_as_uint(f);
    unsigned r = (u + 0x7FFFu + ((u >> 16) & 1u)) >> 16;  // RNE
    return (unsigned short)r;
}
static __device__ __forceinline__ float bf2f(unsigned short h) {
    return __uint_as_float(((unsigned)h) << 16);
}
static __device__ __forceinline__ void split2(float v, unsigned short& h, unsigned short& l) {
    h = f2bf(v);
    l = f2bf(v - bf2f(h));
}

union Pack16 { unsigned short u[16]; uint4 v[2]; };

// A-pack (coords + n2) and B-pack (-2*coords + n2) per point, both clouds.
// Layout: [point][16] bf16 = 32 B per point (2 uint4 = k-half 0, k-half 1).
__global__ void prep_pack(const float* __restrict__ predict, const float* __restrict__ target,
                          unsigned short* __restrict__ ApP, unsigned short* __restrict__ BpP,
                          unsigned short* __restrict__ ApT, unsigned short* __restrict__ BpT,
                          int N)
{
    int i = blockIdx.x * blockDim.x + threadIdx.x;
    if (i >= 2 * N) return;
    const float* src = (i < N) ? predict : target;
    unsigned short* Ap = (i < N) ? ApP : ApT;
    unsigned short* Bp = (i < N) ? BpP : BpT;
    int j = (i < N) ? i : i - N;

    float x = src[3*j], y = src[3*j+1], z = src[3*j+2];
    float n2 = __builtin_fmaf(x, x, __builtin_fmaf(y, y, z*z));

    unsigned short xh,xl,yh,yl,zh,zl,nh,nl,qxh,qxl,qyh,qyl,qzh,qzl;
    split2(x, xh, xl); split2(y, yh, yl); split2(z, zh, zl); split2(n2, nh, nl);
    split2(-2.0f*x, qxh, qxl); split2(-2.0f*y, qyh, qyl); split2(-2.0f*z, qzh, qzl);
    const unsigned short one = f2bf(1.0f);

    Pack16 a, b;
    a.u[0]=xh; a.u[1]=xh; a.u[2]=xl; a.u[3]=xl;
    a.u[4]=yh; a.u[5]=yh; a.u[6]=yl; a.u[7]=yl;
    a.u[8]=zh; a.u[9]=zh; a.u[10]=zl; a.u[11]=zl;
    a.u[12]=nh; a.u[13]=nl; a.u[14]=one; a.u[15]=one;

    b.u[0]=qxh; b.u[1]=qxl; b.u[2]=qxh; b.u[3]=qxl;
    b.u[4]=qyh; b.u[5]=qyl; b.u[6]=qyh; b.u[7]=qyl;
    b.u[8]=qzh; b.u[9]=qzl; b.u[10]=qzh; b.u[11]=qzl;
    b.u[12]=one; b.u[13]=one; b.u[14]=nh; b.u[15]=nl;

    uint4* ad = (uint4*)(Ap + (size_t)j * 16);
    uint4* bd = (uint4*)(Bp + (size_t)j * 16);
    ad[0] = a.v[0]; ad[1] = a.v[1];
    bd[0] = b.v[0]; bd[1] = b.v[1];
}

#define TPB   512
#define WAVES (TPB / 64)
#define AFRAG 2                              // A-frags (32-row strips) per wave
#define ROWS_PER_BLOCK (AFRAG * 32 * WAVES)  // 512
#define SCOLS 1024                           // staged cols per block, 32 KB LDS
#define CGROUPS 16                           // 16384 / 1024

// Grid (N/512, CGROUPS, 2). partials[slot][row], slot = dir*16 + cgroup.
__global__ __launch_bounds__(TPB, 4) void chamfer_main(
    const unsigned short* __restrict__ ApP, const unsigned short* __restrict__ BpP,
    const unsigned short* __restrict__ ApT, const unsigned short* __restrict__ BpT,
    float* __restrict__ partials, int N)
{
    const int dir = blockIdx.z;
    // dir 0: owned rows = predict (Ap), staged cols = target (Bp) -> dist1
    // dir 1: owned rows = target,       staged cols = predict     -> dist2
    const unsigned short* __restrict__ Ap = dir ? ApT : ApP;
    const unsigned short* __restrict__ Bp = dir ? BpP : BpT;

    __shared__ uint4 l4[SCOLS * 2];   // 32 KB, [tile][khalf][lane-in-tile]

    const int tid  = threadIdx.x;
    const int w    = tid >> 6;
    const int lane = tid & 63;
    const int lm   = lane & 31;
    const int lg   = lane >> 5;

    // Stage 1024 staged points, reordered so the compute-loop wave read is
    // linear in lane: uint4 slot (p>>5)*64 + g*32 + (p&31), p=point, g=k-half.
    const uint4* gB = (const uint4*)Bp + (size_t)blockIdx.y * (SCOLS * 2);
    #pragma unroll
    for (int it = 0; it < (SCOLS * 2) / TPB; ++it) {   // 4 iters
        int i = it * TPB + tid;
        uint4 v = gB[i];
        int p = i >> 1, g = i & 1;
        l4[(p >> 5) * 64 + g * 32 + (p & 31)] = v;
    }

    // Owned A-fragments: 2 strips of 32 rows per wave (64 rows/wave).
    const int rowbase = blockIdx.x * ROWS_PER_BLOCK + w * (AFRAG * 32);
    const uint4* A4 = (const uint4*)Ap;
    s16x8 af[AFRAG];
    #pragma unroll
    for (int f = 0; f < AFRAG; ++f)
        af[f] = __builtin_bit_cast(s16x8, A4[(size_t)(rowbase + f * 32 + lm) * 2 + lg]);

    __syncthreads();

    float rm[AFRAG][16];
    #pragma unroll
    for (int f = 0; f < AFRAG; ++f)
        #pragma unroll
        for (int r = 0; r < 16; ++r) rm[f][r] = 3.0e38f;

    const f32x16 zc = {0.f,0.f,0.f,0.f,0.f,0.f,0.f,0.f,0.f,0.f,0.f,0.f,0.f,0.f,0.f,0.f};

    #pragma unroll 4
    for (int t = 0; t < SCOLS / 32; ++t) {   // 32 col-tiles
        // B fragment: col point = t*32+lm, k-half lg -> uint4 slot linear in lane.
        s16x8 b = __builtin_bit_cast(s16x8, l4[t * 64 + lg * 32 + lm]);
        #pragma unroll
        for (int f = 0; f < AFRAG; ++f) {
            f32x16 acc = __builtin_amdgcn_mfma_f32_32x32x16_bf16(af[f], b, zc, 0, 0, 0);
            #pragma unroll
            for (int r = 0; r < 16; ++r)
                rm[f][r] = fminf(rm[f][r], acc[r]);   // per-row running min
        }
    }

    // Butterfly min over the 32 col-lanes (bits 0..4; halves hold disjoint rows).
    #pragma unroll
    for (int m = 1; m <= 16; m <<= 1) {
        #pragma unroll
        for (int f = 0; f < AFRAG; ++f)
            #pragma unroll
            for (int r = 0; r < 16; ++r)
                rm[f][r] = fminf(rm[f][r], __shfl_xor(rm[f][r], m, 64));
    }

    // C/D row decode (verified m74/m101 + R5/R7): row = (r&3)+8*(r>>2)+4*lg.
    const int slot = dir * CGROUPS + blockIdx.y;
    #pragma unroll
    for (int r = 0; r < 16; ++r) {
        int rl = (r & 3) + 8 * (r >> 2) + 4 * lg;
        if (lm == r) {
            #pragma unroll
            for (int f = 0; f < AFRAG; ++f)
                partials[(size_t)slot * N + rowbase + f * 32 + rl] = rm[f][r];
        }
    }
}

// Stage 1: per-row min over CGROUPS slots per dir, clamp, sum -> double/block.
__global__ __launch_bounds__(256) void chamfer_reduce1(
    const float* __restrict__ partials, double* __restrict__ bsum, int N)
{
    const int tid = threadIdx.x;
    const int row = blockIdx.x * 256 + tid;
    float m0 = 3.0e38f, m1 = 3.0e38f;
    #pragma unroll
    for (int k = 0; k < CGROUPS; ++k) {
        m0 = fminf(m0, partials[(size_t)k * N + row]);
        m1 = fminf(m1, partials[(size_t)(CGROUPS + k) * N + row]);
    }
    double s = (double)fmaxf(m0, 0.0f) + (double)fmaxf(m1, 0.0f);
    for (int off = 32; off; off >>= 1) s += __shfl_down(s, off, 64);
    __shared__ double sacc[4];
    if ((tid & 63) == 0) sacc[tid >> 6] = s;
    __syncthreads();
    if (tid == 0) bsum[blockIdx.x] = sacc[0] + sacc[1] + sacc[2] + sacc[3];
}

// Stage 2: sum 64 block partials, write mean(dist1)+mean(dist2).
__global__ void chamfer_reduce2(const double* __restrict__ bsum,
                                float* __restrict__ out, int N) {
    double s = bsum[threadIdx.x];   // 64 threads
    for (int off = 32; off; off >>= 1) s += __shfl_down(s, off, 64);
    if (threadIdx.x == 0) out[0] = (float)(s / (double)N);
}

extern "C" void kernel_launch(void* const* d_in, const int* in_sizes, int n_in,
                              void* d_out, int out_size, void* d_ws, size_t ws_size,
                              hipStream_t stream) {
    const float* predict = (const float*)d_in[0];
    const float* target  = (const float*)d_in[1];
    const int N = in_sizes[0] / 3;   // 16384

    unsigned short* ws16 = (unsigned short*)d_ws;
    unsigned short* ApP = ws16;
    unsigned short* BpP = ws16 + (size_t)1 * N * 16;
    unsigned short* ApT = ws16 + (size_t)2 * N * 16;
    unsigned short* BpT = ws16 + (size_t)3 * N * 16;
    float* partials = (float*)(ws16 + (size_t)4 * N * 16);        // 32*N floats
    double* bsum    = (double*)(partials + (size_t)32 * N);       // 64 doubles

    prep_pack<<<dim3((2 * N + 255) / 256), dim3(256), 0, stream>>>(
        predict, target, ApP, BpP, ApT, BpT, N);

    dim3 grid(N / ROWS_PER_BLOCK, CGROUPS, 2);   // 32 x 16 x 2 = 1024 blocks
    chamfer_main<<<grid, dim3(TPB), 0, stream>>>(ApP, BpP, ApT, BpT, partials, N);

    chamfer_reduce1<<<dim3(N / 256), dim3(256), 0, stream>>>(partials, bsum, N);
    chamfer_reduce2<<<dim3(1), dim3(64), 0, stream>>>(bsum, (float*)d_out, N);
}